// Round 9
// baseline (543.878 us; speedup 1.0000x reference)
//
#include <hip/hip_runtime.h>

typedef _Float16 f16;
typedef _Float16 f16x4 __attribute__((ext_vector_type(4)));
typedef _Float16 f16x8 __attribute__((ext_vector_type(8)));
typedef float f32x4 __attribute__((ext_vector_type(4)));
typedef unsigned int u32;

#define MFMA16(a,b,c) __builtin_amdgcn_mfma_f32_16x16x32_f16(a,b,c,0,0,0)

// raw barrier: orders LDS (lgkmcnt) but does NOT drain vmcnt (neutral vs
// __syncthreads in R3; kept so hG stores never gate a barrier).
#define BAR() asm volatile("s_waitcnt lgkmcnt(0)\n\ts_barrier" ::: "memory")

// packed weight f16-element offsets in d_ws
#define OFF_A0 0
#define OFF_B0 8192
#define OFF_AW 16384
#define OFF_BW 65536
#define OFF_AL 114688
#define OFF_BE 118784
#define OFF_O0 122880
#define OFF_O1 126976
#define OFF_O2 143360
#define PACK_TOTAL 145408
#define OFF_HH 262144                 // h plane (single f16): 8192 mt * 512

struct PackSrcs { const float* p[9]; };

// One fused pack kernel: W[K][N] fp32 -> MFMA fragment order f16.
// frag element (nt,kt,lane,j) = W[kt*32 + (lane>>4)*8 + j][nt*16 + (lane&15)]
// W0 segments: h-rows only, packed into K-tile 0 (packed row k <- source row
// 6+k, k<32); xn rows are handled by the f32 U-precompute in lmsc_rec.
__global__ __launch_bounds__(256) void pack_all(PackSrcs ps, f16* __restrict__ dst){
  int idx = blockIdx.x*256 + threadIdx.x;
  if (idx >= PACK_TOTAL) return;
  const float* src; int base, Kreal, Nreal, KT;
  if (idx < 16384){
    if (idx < 8192){ src=ps.p[0]; base=0; } else { src=ps.p[1]; base=8192; }
    Kreal=38; Nreal=128; KT=2;
  } else if (idx < 65536){
    int s=(idx-16384)>>14; src=ps.p[2]+s*16384; base=16384+s*16384; Kreal=128; Nreal=128; KT=4;
  } else if (idx < 114688){
    int s=(idx-65536)>>14; src=ps.p[3]+s*16384; base=65536+s*16384; Kreal=128; Nreal=128; KT=4;
  } else if (idx < 122880){
    if (idx<118784){ src=ps.p[4]; base=114688; } else { src=ps.p[5]; base=118784; }
    Kreal=128; Nreal=32; KT=4;
  } else if (idx < 126976){
    src=ps.p[6]; base=122880; Kreal=32; Nreal=128; KT=1;
  } else if (idx < 143360){
    src=ps.p[7]; base=126976; Kreal=128; Nreal=128; KT=4;
  } else {
    src=ps.p[8]; base=143360; Kreal=128; Nreal=3; KT=4;
  }
  int local = idx - base;
  int j = local & 7, lane = (local>>3)&63, rem = local>>9;
  int kt = rem % KT, nt = rem / KT;
  int k = kt*32 + ((lane>>4)<<3) + j;
  int n = nt*16 + (lane&15);
  if (base < 16384) k = (k < 32) ? (k + 6) : 99;   // h-rows into tile 0; tile 1 zero
  dst[idx] = (f16)((k<Kreal && n<Nreal) ? src[k*Nreal+n] : 0.f);
}

__device__ __forceinline__ float tanhfast(float x){
  float e = __builtin_amdgcn_exp2f(x * 2.885390082f);   // 2*log2(e)
  return 1.f - 2.f*__builtin_amdgcn_rcpf(e + 1.f);
}
__device__ __forceinline__ float expfast(float x){
  return __builtin_amdgcn_exp2f(x * 1.44269504f);
}

__device__ __forceinline__ f16x8 ldW(const f16* wp, int off, int KT, int nt, int kt, int l){
  return *(const f16x8*)(wp + off + (((nt*KT + kt)*64 + l)<<3));
}

// single-plane quadratic phase (transposed orientation, m=1 per wave)
// bias accumulator-init comes from hoisted REGISTERS (loop-invariant), not LDS.
template<int LAST>
__device__ __forceinline__ void qphase(const f16* __restrict__ Zi, f16* __restrict__ Zo,
                                       const f16x8 (&WA)[4], const f16x8 (&WB)[4],
                                       f32x4 bA4, f32x4 bB4,
                                       int l, int d0, int n16){
  f16x8 Bq[4];
#pragma unroll
  for (int kt=0; kt<4; ++kt) Bq[kt] = *(const f16x8*)(Zi + ((kt*64 + l)<<3));
  f32x4 a = bA4;
  f32x4 c = bB4;
#pragma unroll
  for (int kt=0; kt<4; ++kt){
    a = MFMA16(WA[kt], Bq[kt], a);
    c = MFMA16(WB[kt], Bq[kt], c);
  }
  f16x4 z4;
#pragma unroll
  for (int i=0;i<4;++i){
    float z = LAST ? tanhfast(a[i]*c[i]) : tanhfast(a[i])*tanhfast(c[i]);
    z4[i] = (f16)z;
  }
  int kt_o = d0>>5, lane_o = (((d0&31)>>3)<<4) | n16, j0 = d0&7;
  *(f16x4*)(Zo + ((kt_o*64 + lane_o)<<3) + j0) = z4;
}

// Recurrence: 512 blocks x 512 threads, M=4 grains per block -> 2 blocks/CU,
// 4 waves/SIMD. Each block runs the exact R8 instruction stream; grain-waste
// lanes (n16>=4) compute garbage confined to unused B-columns; only the hG
// store is masked. Two independent phase-streams per CU cross-hide latency.
__global__ __launch_bounds__(512,4)
void lmsc_rec(const float* __restrict__ x, const float* __restrict__ init_ori,
              const f16* __restrict__ wp,
              const float* __restrict__ w0Araw, const float* __restrict__ w0Braw,
              const float* __restrict__ ba0, const float* __restrict__ bas,
              const float* __restrict__ bb0, const float* __restrict__ bbs,
              const float* __restrict__ b_al, const float* __restrict__ b_be,
              f16* __restrict__ hG)
{
  __shared__ __align__(16) f16 S[2][512];      // [hi|lo] h-plane, K=32 rows
  __shared__ __align__(16) f16 Z[2][2048];     // ping-pong, single plane, K=128
  __shared__ float xnL[64][8];                 // xn[t][0..5], sn at [6]
  __shared__ __align__(16) float UA[64][128];  // ba0 + W0A_xn^T @ xn_t (f32)
  __shared__ __align__(16) float UC[64][128];  // bb0 + W0B_xn^T @ xn_t (f32)

  const int tid = (int)threadIdx.x;
  const int l = tid & 63, wid = tid >> 6;      // 8 waves
  const int n16 = l & 15, rhi = l >> 4;
  const int d0 = (wid<<4) + (rhi<<2);          // this wave's 16-dim slice
  const int blk = (int)blockIdx.x;
  const int b = blk >> 6;                      // batch elem (64 blocks each)
  const int Rbase = blk << 2;                  // global grain base (4 grains)
  const int tile16 = blk >> 2, quart = blk & 3;// 16-grain hG tile + quarter

  // ---- register-resident weight fragments (A-frags of W^T) ----
  f16x8 w0A = ldW(wp, OFF_A0, 2, wid, 0, l);
  f16x8 w0B = ldW(wp, OFF_B0, 2, wid, 0, l);
  f16x8 wqA[3][4], wqB[3][4];
#pragma unroll
  for (int ly=0;ly<3;++ly)
#pragma unroll
    for (int kt=0;kt<4;++kt){
      wqA[ly][kt] = ldW(wp, OFF_AW + ly*16384, 4, wid, kt, l);
      wqB[ly][kt] = ldW(wp, OFF_BW + ly*16384, 4, wid, kt, l);
    }
  // ---- hoisted loop-invariant biases (registers, from global) ----
  f32x4 bA_r[3], bB_r[3];
#pragma unroll
  for (int ly=0;ly<3;++ly){
    bA_r[ly] = *(const f32x4*)(bas + ly*128 + d0);
    bB_r[ly] = *(const f32x4*)(bbs + ly*128 + d0);
  }
  const int d0p = (wid<<4) + (rhi<<2);         // == d0; P4 uses waves 0-1 only
  f16x8 wal[4], wbe[4];
  f32x4 uaB = {0,0,0,0}, ubB = {0,0,0,0};
  if (wid < 2){
#pragma unroll
    for (int kt=0;kt<4;++kt){
      wal[kt] = ldW(wp, OFF_AL, 4, wid, kt, l);
      wbe[kt] = ldW(wp, OFF_BE, 4, wid, kt, l);
    }
    uaB = *(const f32x4*)(b_al + d0p);
    ubB = *(const f32x4*)(b_be + d0p);
  }

  // ---- init ----
  if (tid < 64){
    const float* xp = x + (b*64 + tid)*6;
    float s2 = 0.f;
#pragma unroll
    for (int i=0;i<6;++i) s2 += xp[i]*xp[i];
    float sn = sqrtf(s2);
    float inv = 1.f/(sn + 1e-15f);
#pragma unroll
    for (int i=0;i<6;++i) xnL[tid][i] = xp[i]*inv;
    xnL[tid][6] = sn;
  }
  // h state registers (waves 0-1 only): hreg[i] = h[d0p+i][grain n16], n16<4 valid
  float hreg[4] = {0.f,0.f,0.f,0.f};
  if (wid < 2 && n16 < 4){
#pragma unroll
    for (int i=0;i<4;++i){
      int c = d0p + i;
      hreg[i] = (c < 3) ? init_ori[(Rbase + n16)*3 + c] : 0.f;
    }
  }
  __syncthreads();
  // U precompute: 4 threads per dim, 16 t each; W0 xn-rows read once per thread.
  {
    const int dim = tid & 127, t0 = (tid >> 7) << 4;
    float wA[6], wC[6];
#pragma unroll
    for (int k=0;k<6;++k){ wA[k] = w0Araw[k*128+dim]; wC[k] = w0Braw[k*128+dim]; }
    const float bA_ = ba0[dim], bC_ = bb0[dim];
#pragma unroll
    for (int tt=0;tt<16;++tt){
      int t = t0 + tt;
      float aA = bA_, aC = bC_;
#pragma unroll
      for (int k=0;k<6;++k){
        float xv = xnL[t][k];
        aA += xv * wA[k];
        aC += xv * wC[k];
      }
      UA[t][dim] = aA; UC[t][dim] = aC;
    }
  }
  if (tid < 256){
    int r = tid & 15, cc = tid >> 4;
#pragma unroll
    for (int e=0;e<2;++e){
      int c = cc + e*16;
      float h0 = (c < 3 && r < 4) ? init_ori[(Rbase + r)*3 + c] : 0.f;
      f16 hh = (f16)h0, hl = (f16)(h0 - (float)hh);
      int idx = ((((c>>3)<<4) | r)<<3) + (c&7);
      S[0][idx] = hh; S[1][idx] = hl;
    }
  }
  __syncthreads();

  for (int t=0; t<64; ++t){
    // ---- L0: Z0 = tanh(U_A + W0A_h^T@h) * tanh(U_C + W0B_h^T@h) ----
    {
      f16x8 Bh = *(const f16x8*)(&S[0][l<<3]);
      f16x8 Bl = *(const f16x8*)(&S[1][l<<3]);
      f32x4 aH = *(const f32x4*)(&UA[t][d0]);
      f32x4 cH = *(const f32x4*)(&UC[t][d0]);
      f32x4 aL = {0,0,0,0}, cL = {0,0,0,0};
      aH = MFMA16(w0A, Bh, aH); aL = MFMA16(w0A, Bl, aL);
      cH = MFMA16(w0B, Bh, cH); cL = MFMA16(w0B, Bl, cL);
      f16x4 z4;
#pragma unroll
      for (int i=0;i<4;++i)
        z4[i] = (f16)(tanhfast(aH[i]+aL[i]) * tanhfast(cH[i]+cL[i]));
      int kt_o = d0>>5, lane_o = (((d0&31)>>3)<<4) | n16, j0 = d0&7;
      *(f16x4*)(&Z[0][((kt_o*64 + lane_o)<<3) + j0]) = z4;
    }
    BAR();
    qphase<0>(Z[0], Z[1], wqA[0], wqB[0], bA_r[0], bB_r[0], l, d0, n16);
    BAR();
    qphase<0>(Z[1], Z[0], wqA[1], wqB[1], bA_r[1], bB_r[1], l, d0, n16);
    BAR();
    qphase<1>(Z[0], Z[1], wqA[2], wqB[2], bA_r[2], bB_r[2], l, d0, n16);
    BAR();
    // ---- P4: alpha+beta+h-update on waves 0-1 (dims d0p<32), h in registers ----
    if (wid < 2){
      f16x8 q[4];
#pragma unroll
      for (int kt=0;kt<4;++kt) q[kt] = *(const f16x8*)(&Z[1][(kt*64+l)<<3]);
      f32x4 ua = uaB;
      f32x4 ub = ubB;
#pragma unroll
      for (int kt=0;kt<4;++kt){
        ua = MFMA16(wal[kt], q[kt], ua);
        ub = MFMA16(wbe[kt], q[kt], ub);
      }
      float sn = xnL[t][6];
      int mt = tile16*64 + t;
      f16x4 hh4, hl4;
#pragma unroll
      for (int i=0;i<4;++i){
        float alv = expfast(fminf(ua[i], 80.f));
        float bev = tanhfast(ub[i]);
        float hn = __builtin_amdgcn_exp2f(-1.44269504f*alv*sn)*(hreg[i] - bev) + bev;
        hreg[i] = hn;
        f16 hh = (f16)hn; hh4[i] = hh; hl4[i] = (f16)(hn - (float)hh);
      }
      if (t < 63){
        int sb = ((((d0p>>3)<<4) | n16)<<3) + (d0p&7);
        *(f16x4*)(&S[0][sb]) = hh4;
        *(f16x4*)(&S[1][sb]) = hl4;
      }
      if (n16 < 4){   // only the block's 4 valid grains publish h
        int n16g = (quart<<2) | n16;
        int lane_o = ((d0p>>3)<<4) | n16g;
        *(f16x4*)(hG + mt*512 + lane_o*8 + (d0p&7)) = hh4;
      }
    }
    BAR();
  }
}

// Deferred output head: batched GEMM over all 8192 (tile,t) M-tiles, 256 CUs.
__global__ __launch_bounds__(512,4)
void lmsc_out(const f16* __restrict__ wp, const f16* __restrict__ hG,
              const float* __restrict__ bo0, const float* __restrict__ bo1,
              const float* __restrict__ bo2, float* __restrict__ out)
{
  __shared__ __align__(16) f16 o1b[16384];   // [s][kt][lane][8]
  __shared__ __align__(16) f16 o2b[16384];
  const int tid=(int)threadIdx.x, l=tid&63, wid=tid>>6;
  const int n16=l&15, rhi=l>>4;
  const int mtb = (int)blockIdx.x * 8;
  f16x8 W0a = ldW(wp, OFF_O0, 1, wid, 0, l);
  f16x8 W1a[4], W2a[4];
#pragma unroll
  for (int kt=0;kt<4;++kt){ W1a[kt]=ldW(wp,OFF_O1,4,wid,kt,l); W2a[kt]=ldW(wp,OFF_O2,4,0,kt,l); }
  const int d0 = wid*16 + rhi*4;
  const f32x4 b0v = *(const f32x4*)(bo0 + d0);
  const f32x4 b1v = *(const f32x4*)(bo1 + d0);
  const int kt_o = d0>>5, lane_o = (((d0&31)>>3)<<4) + n16, j0 = d0&7;
  // o1 = tanh(h @ W0 + b0), single-plane h
#pragma unroll
  for (int s=0;s<8;++s){
    int mt = mtb + s;
    f16x8 Bh = *(const f16x8*)(hG + ((mt*64+l)<<3));
    f32x4 acc = b0v;
    acc = MFMA16(W0a, Bh, acc);
    f16x4 z4;
#pragma unroll
    for (int i=0;i<4;++i) z4[i] = (f16)tanhfast(acc[i]);
    *(f16x4*)(&o1b[(((s*4+kt_o)*64 + lane_o)<<3) + j0]) = z4;
  }
  __syncthreads();
  // o2 = tanh(o1 @ W1 + b1)
#pragma unroll
  for (int s=0;s<8;++s){
    f32x4 acc = b1v;
#pragma unroll
    for (int kt=0;kt<4;++kt){
      f16x8 B = *(const f16x8*)(&o1b[((s*4+kt)*64 + l)<<3]);
      acc = MFMA16(W1a[kt], B, acc);
    }
    f16x4 z4;
#pragma unroll
    for (int i=0;i<4;++i) z4[i] = (f16)tanhfast(acc[i]);
    *(f16x4*)(&o2b[(((s*4+kt_o)*64 + lane_o)<<3) + j0]) = z4;
  }
  __syncthreads();
  // o3 = o2 @ W2 + b2 -> out; wave w handles subtile w
  {
    f32x4 acc = {0,0,0,0};
#pragma unroll
    for (int kt=0;kt<4;++kt){
      f16x8 B = *(const f16x8*)(&o2b[((wid*4+kt)*64 + l)<<3]);
      acc = MFMA16(W2a[kt], B, acc);
    }
    if (l < 16){
      int mt = mtb + wid, grow = (mt>>6)*16 + n16, tt = mt & 63;
#pragma unroll
      for (int i=0;i<3;++i)
        out[(grow*64 + tt)*3 + i] = acc[i] + bo2[i];
    }
  }
}

extern "C" void kernel_launch(void* const* d_in, const int* in_sizes, int n_in,
                              void* d_out, int out_size, void* d_ws, size_t ws_size,
                              hipStream_t stream){
  const float* x        = (const float*)d_in[0];
  const float* init_ori = (const float*)d_in[1];
  f16* wp = (f16*)d_ws;

  PackSrcs ps;
  ps.p[0] = (const float*)d_in[2];   // qbA_W0
  ps.p[1] = (const float*)d_in[6];   // qbB_W0
  ps.p[2] = (const float*)d_in[4];   // qbA_Ws
  ps.p[3] = (const float*)d_in[8];   // qbB_Ws
  ps.p[4] = (const float*)d_in[10];  // alpha_W
  ps.p[5] = (const float*)d_in[12];  // beta_W
  ps.p[6] = (const float*)d_in[14];  // out_W0
  ps.p[7] = (const float*)d_in[16];  // out_W1
  ps.p[8] = (const float*)d_in[18];  // out_W2
  pack_all<<<(PACK_TOTAL+255)/256, 256, 0, stream>>>(ps, wp);

  lmsc_rec<<<512,512,0,stream>>>(x, init_ori, wp,
      (const float*)d_in[2],  (const float*)d_in[6],   // raw W0 for U-precompute
      (const float*)d_in[3],  (const float*)d_in[5],   // qbA_b0, qbA_bs
      (const float*)d_in[7],  (const float*)d_in[9],   // qbB_b0, qbB_bs
      (const float*)d_in[11], (const float*)d_in[13],  // alpha_b, beta_b
      wp + OFF_HH);
  lmsc_out<<<1024,512,0,stream>>>(wp, wp + OFF_HH,
      (const float*)d_in[15], (const float*)d_in[17], (const float*)d_in[19],
      (float*)d_out);
}

// Round 10
// 268.168 us; speedup vs baseline: 2.0281x; 2.0281x over previous
//
#include <hip/hip_runtime.h>

typedef _Float16 f16;
typedef _Float16 f16x4 __attribute__((ext_vector_type(4)));
typedef _Float16 f16x8 __attribute__((ext_vector_type(8)));
typedef float f32x4 __attribute__((ext_vector_type(4)));
typedef unsigned int u32;

#define MFMA16(a,b,c) __builtin_amdgcn_mfma_f32_16x16x32_f16(a,b,c,0,0,0)

// raw barrier: orders LDS (lgkmcnt) but does NOT drain vmcnt.
#define BAR() asm volatile("s_waitcnt lgkmcnt(0)\n\ts_barrier" ::: "memory")

// packed weight f16-element offsets in d_ws
#define OFF_A0 0
#define OFF_B0 8192
#define OFF_AW 16384
#define OFF_BW 65536
#define OFF_AL 114688
#define OFF_BE 118784
#define OFF_O0 122880
#define OFF_O1 126976
#define OFF_O2 143360
#define PACK_TOTAL 145408

struct PackSrcs { const float* p[9]; };

// One fused pack kernel: W[K][N] fp32 -> MFMA fragment order f16.
// frag element (nt,kt,lane,j) = W[kt*32 + (lane>>4)*8 + j][nt*16 + (lane&15)]
// W0 segments: h-rows only, packed into K-tile 0 (packed row k <- source row
// 6+k, k<32); xn rows are handled by the f32 U-precompute in lmsc_rec.
__global__ __launch_bounds__(256) void pack_all(PackSrcs ps, f16* __restrict__ dst){
  int idx = blockIdx.x*256 + threadIdx.x;
  if (idx >= PACK_TOTAL) return;
  const float* src; int base, Kreal, Nreal, KT;
  if (idx < 16384){
    if (idx < 8192){ src=ps.p[0]; base=0; } else { src=ps.p[1]; base=8192; }
    Kreal=38; Nreal=128; KT=2;
  } else if (idx < 65536){
    int s=(idx-16384)>>14; src=ps.p[2]+s*16384; base=16384+s*16384; Kreal=128; Nreal=128; KT=4;
  } else if (idx < 114688){
    int s=(idx-65536)>>14; src=ps.p[3]+s*16384; base=65536+s*16384; Kreal=128; Nreal=128; KT=4;
  } else if (idx < 122880){
    if (idx<118784){ src=ps.p[4]; base=114688; } else { src=ps.p[5]; base=118784; }
    Kreal=128; Nreal=32; KT=4;
  } else if (idx < 126976){
    src=ps.p[6]; base=122880; Kreal=32; Nreal=128; KT=1;
  } else if (idx < 143360){
    src=ps.p[7]; base=126976; Kreal=128; Nreal=128; KT=4;
  } else {
    src=ps.p[8]; base=143360; Kreal=128; Nreal=3; KT=4;
  }
  int local = idx - base;
  int j = local & 7, lane = (local>>3)&63, rem = local>>9;
  int kt = rem % KT, nt = rem / KT;
  int k = kt*32 + ((lane>>4)<<3) + j;
  int n = nt*16 + (lane&15);
  if (base < 16384) k = (k < 32) ? (k + 6) : 99;   // h-rows into tile 0; tile 1 zero
  dst[idx] = (f16)((k<Kreal && n<Nreal) ? src[k*Nreal+n] : 0.f);
}

__device__ __forceinline__ float tanhfast(float x){
  float e = __builtin_amdgcn_exp2f(x * 2.885390082f);   // 2*log2(e)
  return 1.f - 2.f*__builtin_amdgcn_rcpf(e + 1.f);
}
__device__ __forceinline__ float expfast(float x){
  return __builtin_amdgcn_exp2f(x * 1.44269504f);
}

__device__ __forceinline__ f16x8 ldW(const f16* wp, int off, int KT, int nt, int kt, int l){
  return *(const f16x8*)(wp + off + (((nt*KT + kt)*64 + l)<<3));
}

// single-plane quadratic phase (transposed orientation, m=1 per wave)
// bias accumulator-init from hoisted registers (loop-invariant).
template<int LAST>
__device__ __forceinline__ void qphase(const f16* __restrict__ Zi, f16* __restrict__ Zo,
                                       const f16x8 (&WA)[4], const f16x8 (&WB)[4],
                                       f32x4 bA4, f32x4 bB4,
                                       int l, int d0, int n16){
  f16x8 Bq[4];
#pragma unroll
  for (int kt=0; kt<4; ++kt) Bq[kt] = *(const f16x8*)(Zi + ((kt*64 + l)<<3));
  f32x4 a = bA4;
  f32x4 c = bB4;
#pragma unroll
  for (int kt=0; kt<4; ++kt){
    a = MFMA16(WA[kt], Bq[kt], a);
    c = MFMA16(WB[kt], Bq[kt], c);
  }
  f16x4 z4;
#pragma unroll
  for (int i=0;i<4;++i){
    float z = LAST ? tanhfast(a[i]*c[i]) : tanhfast(a[i])*tanhfast(c[i]);
    z4[i] = (f16)z;
  }
  int kt_o = d0>>5, lane_o = (((d0&31)>>3)<<4) | n16, j0 = d0&7;
  *(f16x4*)(Zo + ((kt_o*64 + lane_o)<<3) + j0) = z4;
}

// Recurrence + fused output head: 128 blocks x 512 threads (8 waves, 2/SIMD).
// R8 structure for L0/q1/q2/q3. The P4 "superphase" runs four concurrent
// wave-roles, with the output head pipelined 3 timesteps deep on the
// otherwise-idle waves:
//   waves 0-1: alpha/beta GEMM + h(t) update -> S[(t+1)&1] (hi/lo planes)
//   waves 4-5: o1(t-1) = tanh(h @ W0 + b0)   reads S[t&1][0], writes o1buf[(t+1)&1]
//   waves 2-3: o2(t-2) = tanh(o1 @ W1 + b1)  reads o1buf[t&1], writes o2buf[t&1]
//   wave  6  : o3(t-3) = o2 @ W2 + b2 -> out reads o2buf[(t+1)&1]
// Loop runs 67 iterations (3 tail iterations drain the pipeline).
__global__ __launch_bounds__(512,2)
void lmsc_rec(const float* __restrict__ x, const float* __restrict__ init_ori,
              const f16* __restrict__ wp,
              const float* __restrict__ w0Araw, const float* __restrict__ w0Braw,
              const float* __restrict__ ba0, const float* __restrict__ bas,
              const float* __restrict__ bb0, const float* __restrict__ bbs,
              const float* __restrict__ b_al, const float* __restrict__ b_be,
              const float* __restrict__ bo0, const float* __restrict__ bo1,
              const float* __restrict__ bo2, float* __restrict__ out)
{
  __shared__ __align__(16) f16 S[2][2][512];   // [parity][hi|lo] h-plane, K=32
  __shared__ __align__(16) f16 Z[2][2048];     // ping-pong, single plane, K=128
  __shared__ __align__(16) f16 o1buf[2][2048]; // [parity] o1 frag plane
  __shared__ __align__(16) f16 o2buf[2][2048]; // [parity] o2 frag plane
  __shared__ float xnL[64][8];                 // xn[t][0..5], sn at [6]
  __shared__ __align__(16) float UA[64][128];  // ba0 + W0A_xn^T @ xn_t (f32)
  __shared__ __align__(16) float UC[64][128];  // bb0 + W0B_xn^T @ xn_t (f32)

  const int tid = (int)threadIdx.x;
  const int l = tid & 63, wid = tid >> 6;      // 8 waves
  const int n16 = l & 15, rhi = l >> 4;
  const int d0 = (wid<<4) + (rhi<<2);          // this wave's 16-dim slice
  const int tile = (int)blockIdx.x, b = tile >> 4, Rbase = tile << 4;

  // ---- register-resident weight fragments (A-frags of W^T) ----
  f16x8 w0A = ldW(wp, OFF_A0, 2, wid, 0, l);
  f16x8 w0B = ldW(wp, OFF_B0, 2, wid, 0, l);
  f16x8 wqA[3][4], wqB[3][4];
#pragma unroll
  for (int ly=0;ly<3;++ly)
#pragma unroll
    for (int kt=0;kt<4;++kt){
      wqA[ly][kt] = ldW(wp, OFF_AW + ly*16384, 4, wid, kt, l);
      wqB[ly][kt] = ldW(wp, OFF_BW + ly*16384, 4, wid, kt, l);
    }
  // ---- hoisted loop-invariant biases (registers, from global) ----
  f32x4 bA_r[3], bB_r[3];
#pragma unroll
  for (int ly=0;ly<3;++ly){
    bA_r[ly] = *(const f32x4*)(bas + ly*128 + d0);
    bB_r[ly] = *(const f32x4*)(bbs + ly*128 + d0);
  }
  const int d0p = (wid<<4) + (rhi<<2);
  // role weights (branch-disjoint; compiler may overlay registers)
  f16x8 wal[4], wbe[4];
  f32x4 uaB = {0,0,0,0}, ubB = {0,0,0,0};
  if (wid < 2){
#pragma unroll
    for (int kt=0;kt<4;++kt){
      wal[kt] = ldW(wp, OFF_AL, 4, wid, kt, l);
      wbe[kt] = ldW(wp, OFF_BE, 4, wid, kt, l);
    }
    uaB = *(const f32x4*)(b_al + d0p);
    ubB = *(const f32x4*)(b_be + d0p);
  }
  f16x8 wo1[4][4]; f32x4 bo1r[4];              // waves 2-3: o2 layer
  if (wid == 2 || wid == 3){
#pragma unroll
    for (int j=0;j<4;++j){
      int nt = (wid-2)*4 + j;
#pragma unroll
      for (int kt=0;kt<4;++kt) wo1[j][kt] = ldW(wp, OFF_O1, 4, nt, kt, l);
      bo1r[j] = *(const f32x4*)(bo1 + nt*16 + (rhi<<2));
    }
  }
  f16x8 wo0[4]; f32x4 bo0r[4];                 // waves 4-5: o1 layer
  if (wid == 4 || wid == 5){
#pragma unroll
    for (int j=0;j<4;++j){
      int nt = (wid-4)*4 + j;
      wo0[j] = ldW(wp, OFF_O0, 1, nt, 0, l);
      bo0r[j] = *(const f32x4*)(bo0 + nt*16 + (rhi<<2));
    }
  }
  f16x8 wo2[4]; float b2r0=0.f, b2r1=0.f, b2r2=0.f;  // wave 6: o3 layer
  if (wid == 6){
#pragma unroll
    for (int kt=0;kt<4;++kt) wo2[kt] = ldW(wp, OFF_O2, 4, 0, kt, l);
    b2r0 = bo2[0]; b2r1 = bo2[1]; b2r2 = bo2[2];
  }

  // ---- init ----
  if (tid < 64){
    const float* xp = x + (b*64 + tid)*6;
    float s2 = 0.f;
#pragma unroll
    for (int i=0;i<6;++i) s2 += xp[i]*xp[i];
    float sn = sqrtf(s2);
    float inv = 1.f/(sn + 1e-15f);
#pragma unroll
    for (int i=0;i<6;++i) xnL[tid][i] = xp[i]*inv;
    xnL[tid][6] = sn;
  }
  // h state registers (waves 0-1 only): hreg[i] = h[d0p+i][n16]
  float hreg[4] = {0.f,0.f,0.f,0.f};
  if (wid < 2){
#pragma unroll
    for (int i=0;i<4;++i){
      int c = d0p + i;
      hreg[i] = (c < 3) ? init_ori[(Rbase + n16)*3 + c] : 0.f;
    }
  }
  __syncthreads();
  // U precompute: 4 threads per dim, 16 t each.
  {
    const int dim = tid & 127, t0 = (tid >> 7) << 4;
    float wA[6], wC[6];
#pragma unroll
    for (int k=0;k<6;++k){ wA[k] = w0Araw[k*128+dim]; wC[k] = w0Braw[k*128+dim]; }
    const float bA_ = ba0[dim], bC_ = bb0[dim];
#pragma unroll
    for (int tt=0;tt<16;++tt){
      int t = t0 + tt;
      float aA = bA_, aC = bC_;
#pragma unroll
      for (int k=0;k<6;++k){
        float xv = xnL[t][k];
        aA += xv * wA[k];
        aC += xv * wC[k];
      }
      UA[t][dim] = aA; UC[t][dim] = aC;
    }
  }
  if (tid < 256){
    int r = tid & 15, cc = tid >> 4;
#pragma unroll
    for (int e=0;e<2;++e){
      int c = cc + e*16;
      float h0 = (c < 3) ? init_ori[(Rbase + r)*3 + c] : 0.f;
      f16 hh = (f16)h0, hl = (f16)(h0 - (float)hh);
      int idx = ((((c>>3)<<4) | r)<<3) + (c&7);
      S[0][0][idx] = hh; S[0][1][idx] = hl;
    }
  }
  __syncthreads();

  for (int t=0; t<67; ++t){
    if (t < 64){
      // ---- L0: Z0 = tanh(U_A + W0A_h^T@h) * tanh(U_C + W0B_h^T@h) ----
      {
        f16x8 Bh = *(const f16x8*)(&S[t&1][0][l<<3]);
        f16x8 Bl = *(const f16x8*)(&S[t&1][1][l<<3]);
        f32x4 aH = *(const f32x4*)(&UA[t][d0]);
        f32x4 cH = *(const f32x4*)(&UC[t][d0]);
        f32x4 aL = {0,0,0,0}, cL = {0,0,0,0};
        aH = MFMA16(w0A, Bh, aH); aL = MFMA16(w0A, Bl, aL);
        cH = MFMA16(w0B, Bh, cH); cL = MFMA16(w0B, Bl, cL);
        f16x4 z4;
#pragma unroll
        for (int i=0;i<4;++i)
          z4[i] = (f16)(tanhfast(aH[i]+aL[i]) * tanhfast(cH[i]+cL[i]));
        int kt_o = d0>>5, lane_o = (((d0&31)>>3)<<4) | n16, j0 = d0&7;
        *(f16x4*)(&Z[0][((kt_o*64 + lane_o)<<3) + j0]) = z4;
      }
      BAR();
      qphase<0>(Z[0], Z[1], wqA[0], wqB[0], bA_r[0], bB_r[0], l, d0, n16);
      BAR();
      qphase<0>(Z[1], Z[0], wqA[1], wqB[1], bA_r[1], bB_r[1], l, d0, n16);
      BAR();
      qphase<1>(Z[0], Z[1], wqA[2], wqB[2], bA_r[2], bB_r[2], l, d0, n16);
      BAR();
    }
    // ---- P4 superphase ----
    if (t < 64 && wid < 2){
      // alpha+beta + h-update; h(t) -> S[(t+1)&1]
      f16x8 q[4];
#pragma unroll
      for (int kt=0;kt<4;++kt) q[kt] = *(const f16x8*)(&Z[1][(kt*64+l)<<3]);
      f32x4 ua = uaB;
      f32x4 ub = ubB;
#pragma unroll
      for (int kt=0;kt<4;++kt){
        ua = MFMA16(wal[kt], q[kt], ua);
        ub = MFMA16(wbe[kt], q[kt], ub);
      }
      float sn = xnL[t][6];
      f16x4 hh4, hl4;
#pragma unroll
      for (int i=0;i<4;++i){
        float alv = expfast(fminf(ua[i], 80.f));
        float bev = tanhfast(ub[i]);
        float hn = __builtin_amdgcn_exp2f(-1.44269504f*alv*sn)*(hreg[i] - bev) + bev;
        hreg[i] = hn;
        f16 hh = (f16)hn; hh4[i] = hh; hl4[i] = (f16)(hn - (float)hh);
      }
      int sb = ((((d0p>>3)<<4) | n16)<<3) + (d0p&7);
      *(f16x4*)(&S[(t+1)&1][0][sb]) = hh4;
      *(f16x4*)(&S[(t+1)&1][1][sb]) = hl4;
    }
    if ((wid == 4 || wid == 5) && t >= 1 && t <= 64){
      // o1(t-1) = tanh(h(t-1) @ W0 + b0); h(t-1) lives in S[t&1][0]
      f16x8 Bh = *(const f16x8*)(&S[t&1][0][l<<3]);
      f16* o1w = &o1buf[(t+1)&1][0];
#pragma unroll
      for (int j=0;j<4;++j){
        f32x4 acc = bo0r[j];
        acc = MFMA16(wo0[j], Bh, acc);
        f16x4 z4;
#pragma unroll
        for (int i=0;i<4;++i) z4[i] = (f16)tanhfast(acc[i]);
        int d0s = ((wid-4)*4 + j)*16 + (rhi<<2);
        int kt_o = d0s>>5, lane_o = (((d0s&31)>>3)<<4) | n16, j0 = d0s&7;
        *(f16x4*)(o1w + ((kt_o*64 + lane_o)<<3) + j0) = z4;
      }
    }
    if ((wid == 2 || wid == 3) && t >= 2 && t <= 65){
      // o2(t-2) = tanh(o1(t-2) @ W1 + b1); o1(t-2) lives in o1buf[t&1]
      f16x8 Bq[4];
#pragma unroll
      for (int kt=0;kt<4;++kt) Bq[kt] = *(const f16x8*)(&o1buf[t&1][(kt*64+l)<<3]);
      f16* o2w = &o2buf[t&1][0];
#pragma unroll
      for (int j=0;j<4;++j){
        f32x4 acc = bo1r[j];
#pragma unroll
        for (int kt=0;kt<4;++kt) acc = MFMA16(wo1[j][kt], Bq[kt], acc);
        f16x4 z4;
#pragma unroll
        for (int i=0;i<4;++i) z4[i] = (f16)tanhfast(acc[i]);
        int d0s = ((wid-2)*4 + j)*16 + (rhi<<2);
        int kt_o = d0s>>5, lane_o = (((d0s&31)>>3)<<4) | n16, j0 = d0s&7;
        *(f16x4*)(o2w + ((kt_o*64 + lane_o)<<3) + j0) = z4;
      }
    }
    if (wid == 6 && t >= 3){
      // o3(t-3) = o2(t-3) @ W2 + b2 -> out; o2(t-3) lives in o2buf[(t+1)&1]
      f16x8 Bq[4];
#pragma unroll
      for (int kt=0;kt<4;++kt) Bq[kt] = *(const f16x8*)(&o2buf[(t+1)&1][(kt*64+l)<<3]);
      f32x4 acc = {0,0,0,0};
#pragma unroll
      for (int kt=0;kt<4;++kt) acc = MFMA16(wo2[kt], Bq[kt], acc);
      if (l < 16){
        int t3 = t - 3;
        float* op = out + ((Rbase + l)*64 + t3)*3;
        op[0] = acc[0] + b2r0;
        op[1] = acc[1] + b2r1;
        op[2] = acc[2] + b2r2;
      }
    }
    BAR();
  }
}

extern "C" void kernel_launch(void* const* d_in, const int* in_sizes, int n_in,
                              void* d_out, int out_size, void* d_ws, size_t ws_size,
                              hipStream_t stream){
  const float* x        = (const float*)d_in[0];
  const float* init_ori = (const float*)d_in[1];
  f16* wp = (f16*)d_ws;

  PackSrcs ps;
  ps.p[0] = (const float*)d_in[2];   // qbA_W0
  ps.p[1] = (const float*)d_in[6];   // qbB_W0
  ps.p[2] = (const float*)d_in[4];   // qbA_Ws
  ps.p[3] = (const float*)d_in[8];   // qbB_Ws
  ps.p[4] = (const float*)d_in[10];  // alpha_W
  ps.p[5] = (const float*)d_in[12];  // beta_W
  ps.p[6] = (const float*)d_in[14];  // out_W0
  ps.p[7] = (const float*)d_in[16];  // out_W1
  ps.p[8] = (const float*)d_in[18];  // out_W2
  pack_all<<<(PACK_TOTAL+255)/256, 256, 0, stream>>>(ps, wp);

  lmsc_rec<<<128,512,0,stream>>>(x, init_ori, wp,
      (const float*)d_in[2],  (const float*)d_in[6],   // raw W0 for U-precompute
      (const float*)d_in[3],  (const float*)d_in[5],   // qbA_b0, qbA_bs
      (const float*)d_in[7],  (const float*)d_in[9],   // qbB_b0, qbB_bs
      (const float*)d_in[11], (const float*)d_in[13],  // alpha_b, beta_b
      (const float*)d_in[15], (const float*)d_in[17], (const float*)d_in[19],
      (float*)d_out);
}

// Round 11
// 166.432 us; speedup vs baseline: 3.2679x; 1.6113x over previous
//
#include <hip/hip_runtime.h>

typedef _Float16 f16;
typedef _Float16 f16x4 __attribute__((ext_vector_type(4)));
typedef _Float16 f16x8 __attribute__((ext_vector_type(8)));
typedef float f32x4 __attribute__((ext_vector_type(4)));
typedef unsigned int u32;

#define MFMA16(a,b,c) __builtin_amdgcn_mfma_f32_16x16x32_f16(a,b,c,0,0,0)

// raw barrier: orders LDS (lgkmcnt) but does NOT drain vmcnt.
#define BAR() asm volatile("s_waitcnt lgkmcnt(0)\n\ts_barrier" ::: "memory")

// packed weight f16-element offsets in d_ws
#define OFF_A0 0
#define OFF_B0 8192
#define OFF_AW 16384
#define OFF_BW 65536
#define OFF_AL 114688
#define OFF_BE 118784
#define OFF_O0 122880
#define OFF_O1 126976
#define OFF_O2 143360
#define PACK_TOTAL 145408
#define OUT_F16 22528                 // O0(4096)+O1(16384)+O2(2048) contiguous

struct PackSrcs { const float* p[9]; };

// One fused pack kernel: W[K][N] fp32 -> MFMA fragment order f16.
// frag element (nt,kt,lane,j) = W[kt*32 + (lane>>4)*8 + j][nt*16 + (lane&15)]
// W0 segments: h-rows only, packed into K-tile 0 (packed row k <- source row
// 6+k, k<32); xn rows are handled by the f32 U-precompute in lmsc_rec.
__global__ __launch_bounds__(256) void pack_all(PackSrcs ps, f16* __restrict__ dst){
  int idx = blockIdx.x*256 + threadIdx.x;
  if (idx >= PACK_TOTAL) return;
  const float* src; int base, Kreal, Nreal, KT;
  if (idx < 16384){
    if (idx < 8192){ src=ps.p[0]; base=0; } else { src=ps.p[1]; base=8192; }
    Kreal=38; Nreal=128; KT=2;
  } else if (idx < 65536){
    int s=(idx-16384)>>14; src=ps.p[2]+s*16384; base=16384+s*16384; Kreal=128; Nreal=128; KT=4;
  } else if (idx < 114688){
    int s=(idx-65536)>>14; src=ps.p[3]+s*16384; base=65536+s*16384; Kreal=128; Nreal=128; KT=4;
  } else if (idx < 122880){
    if (idx<118784){ src=ps.p[4]; base=114688; } else { src=ps.p[5]; base=118784; }
    Kreal=128; Nreal=32; KT=4;
  } else if (idx < 126976){
    src=ps.p[6]; base=122880; Kreal=32; Nreal=128; KT=1;
  } else if (idx < 143360){
    src=ps.p[7]; base=126976; Kreal=128; Nreal=128; KT=4;
  } else {
    src=ps.p[8]; base=143360; Kreal=128; Nreal=3; KT=4;
  }
  int local = idx - base;
  int j = local & 7, lane = (local>>3)&63, rem = local>>9;
  int kt = rem % KT, nt = rem / KT;
  int k = kt*32 + ((lane>>4)<<3) + j;
  int n = nt*16 + (lane&15);
  if (base < 16384) k = (k < 32) ? (k + 6) : 99;   // h-rows into tile 0; tile 1 zero
  dst[idx] = (f16)((k<Kreal && n<Nreal) ? src[k*Nreal+n] : 0.f);
}

__device__ __forceinline__ float tanhfast(float x){
  float e = __builtin_amdgcn_exp2f(x * 2.885390082f);   // 2*log2(e)
  return 1.f - 2.f*__builtin_amdgcn_rcpf(e + 1.f);
}
__device__ __forceinline__ float expfast(float x){
  return __builtin_amdgcn_exp2f(x * 1.44269504f);
}

__device__ __forceinline__ f16x8 ldW(const f16* wp, int off, int KT, int nt, int kt, int l){
  return *(const f16x8*)(wp + off + (((nt*KT + kt)*64 + l)<<3));
}
__device__ __forceinline__ f16x8 ldWs(const f16* ws, int off, int KT, int nt, int kt, int l){
  return *(const f16x8*)(ws + off + (((nt*KT + kt)*64 + l)<<3));
}

// single-plane quadratic phase (transposed orientation, m=1 per wave)
// bias accumulator-init from hoisted registers (loop-invariant).
template<int LAST>
__device__ __forceinline__ void qphase(const f16* __restrict__ Zi, f16* __restrict__ Zo,
                                       const f16x8 (&WA)[4], const f16x8 (&WB)[4],
                                       f32x4 bA4, f32x4 bB4,
                                       int l, int d0, int n16){
  f16x8 Bq[4];
#pragma unroll
  for (int kt=0; kt<4; ++kt) Bq[kt] = *(const f16x8*)(Zi + ((kt*64 + l)<<3));
  f32x4 a = bA4;
  f32x4 c = bB4;
#pragma unroll
  for (int kt=0; kt<4; ++kt){
    a = MFMA16(WA[kt], Bq[kt], a);
    c = MFMA16(WB[kt], Bq[kt], c);
  }
  f16x4 z4;
#pragma unroll
  for (int i=0;i<4;++i){
    float z = LAST ? tanhfast(a[i]*c[i]) : tanhfast(a[i])*tanhfast(c[i]);
    z4[i] = (f16)z;
  }
  int kt_o = d0>>5, lane_o = (((d0&31)>>3)<<4) | n16, j0 = d0&7;
  *(f16x4*)(Zo + ((kt_o*64 + lane_o)<<3) + j0) = z4;
}

// Recurrence + fused output head: 128 blocks x 512 threads (8 waves, 2/SIMD).
// R8 structure for L0/q1/q2/q3. P4 superphase wave-roles (out head pipelined
// 3 timesteps deep on the otherwise-idle waves):
//   waves 0-1: alpha/beta GEMM + h(t) update -> S[(t+1)&1]
//   waves 4-5: o1(t-1) reads S[t&1][0] -> o1buf[(t+1)&1]
//   waves 2-3: o2(t-2) reads o1buf[t&1] -> o2buf[t&1]
//   wave  6  : o3(t-3) reads o2buf[(t+1)&1] -> out (global)
// Out-layer WEIGHTS live in LDS (staged once at init) so role code adds no
// register pressure (R10's failure mode: 64-VGPR role arrays -> spill).
// Loop runs 67 iterations (3 tail iterations drain the pipeline).
__global__ __launch_bounds__(512,2)
void lmsc_rec(const float* __restrict__ x, const float* __restrict__ init_ori,
              const f16* __restrict__ wp,
              const float* __restrict__ w0Araw, const float* __restrict__ w0Braw,
              const float* __restrict__ ba0, const float* __restrict__ bas,
              const float* __restrict__ bb0, const float* __restrict__ bbs,
              const float* __restrict__ b_al, const float* __restrict__ b_be,
              const float* __restrict__ bo0, const float* __restrict__ bo1,
              const float* __restrict__ bo2, float* __restrict__ out)
{
  __shared__ __align__(16) f16 S[2][2][512];   // [parity][hi|lo] h-plane, K=32
  __shared__ __align__(16) f16 Z[2][2048];     // ping-pong, single plane, K=128
  __shared__ __align__(16) f16 o1buf[2][2048]; // [parity] o1 frag plane
  __shared__ __align__(16) f16 o2buf[2][2048]; // [parity] o2 frag plane
  __shared__ __align__(16) f16 WOs[OUT_F16];   // out-head weights: O0|O1|O2
  __shared__ float xnL[64][8];                 // xn[t][0..5], sn at [6]
  __shared__ __align__(16) float UA[64][128];  // ba0 + W0A_xn^T @ xn_t (f32)
  __shared__ __align__(16) float UC[64][128];  // bb0 + W0B_xn^T @ xn_t (f32)

  const int tid = (int)threadIdx.x;
  const int l = tid & 63, wid = tid >> 6;      // 8 waves
  const int n16 = l & 15, rhi = l >> 4;
  const int d0 = (wid<<4) + (rhi<<2);          // this wave's 16-dim slice
  const int tile = (int)blockIdx.x, b = tile >> 4, Rbase = tile << 4;

  // ---- register-resident weight fragments (A-frags of W^T) ----
  f16x8 w0A = ldW(wp, OFF_A0, 2, wid, 0, l);
  f16x8 w0B = ldW(wp, OFF_B0, 2, wid, 0, l);
  f16x8 wqA[3][4], wqB[3][4];
#pragma unroll
  for (int ly=0;ly<3;++ly)
#pragma unroll
    for (int kt=0;kt<4;++kt){
      wqA[ly][kt] = ldW(wp, OFF_AW + ly*16384, 4, wid, kt, l);
      wqB[ly][kt] = ldW(wp, OFF_BW + ly*16384, 4, wid, kt, l);
    }
  // ---- hoisted loop-invariant biases (registers, from global) ----
  f32x4 bA_r[3], bB_r[3];
#pragma unroll
  for (int ly=0;ly<3;++ly){
    bA_r[ly] = *(const f32x4*)(bas + ly*128 + d0);
    bB_r[ly] = *(const f32x4*)(bbs + ly*128 + d0);
  }
  const int d0p = (wid<<4) + (rhi<<2);
  // role registers (small only; weights come from LDS)
  f16x8 wal[4], wbe[4];
  f32x4 uaB = {0,0,0,0}, ubB = {0,0,0,0};
  if (wid < 2){
#pragma unroll
    for (int kt=0;kt<4;++kt){
      wal[kt] = ldW(wp, OFF_AL, 4, wid, kt, l);
      wbe[kt] = ldW(wp, OFF_BE, 4, wid, kt, l);
    }
    uaB = *(const f32x4*)(b_al + d0p);
    ubB = *(const f32x4*)(b_be + d0p);
  }
  f32x4 bo1r[4];                               // waves 2-3: o2 layer biases
  if (wid == 2 || wid == 3){
#pragma unroll
    for (int j=0;j<4;++j)
      bo1r[j] = *(const f32x4*)(bo1 + ((wid-2)*4 + j)*16 + (rhi<<2));
  }
  f32x4 bo0r[4];                               // waves 4-5: o1 layer biases
  if (wid == 4 || wid == 5){
#pragma unroll
    for (int j=0;j<4;++j)
      bo0r[j] = *(const f32x4*)(bo0 + ((wid-4)*4 + j)*16 + (rhi<<2));
  }
  float b2r0=0.f, b2r1=0.f, b2r2=0.f;          // wave 6: o3 biases
  if (wid == 6){ b2r0 = bo2[0]; b2r1 = bo2[1]; b2r2 = bo2[2]; }

  // ---- init ----
  // stage out-head weights (contiguous in wp) into LDS
  for (int i = tid; i < OUT_F16/8; i += 512)
    *(f16x8*)(&WOs[i<<3]) = *(const f16x8*)(wp + OFF_O0 + (i<<3));
  if (tid < 64){
    const float* xp = x + (b*64 + tid)*6;
    float s2 = 0.f;
#pragma unroll
    for (int i=0;i<6;++i) s2 += xp[i]*xp[i];
    float sn = sqrtf(s2);
    float inv = 1.f/(sn + 1e-15f);
#pragma unroll
    for (int i=0;i<6;++i) xnL[tid][i] = xp[i]*inv;
    xnL[tid][6] = sn;
  }
  // h state registers (waves 0-1 only): hreg[i] = h[d0p+i][n16]
  float hreg[4] = {0.f,0.f,0.f,0.f};
  if (wid < 2){
#pragma unroll
    for (int i=0;i<4;++i){
      int c = d0p + i;
      hreg[i] = (c < 3) ? init_ori[(Rbase + n16)*3 + c] : 0.f;
    }
  }
  __syncthreads();
  // U precompute: 4 threads per dim, 16 t each.
  {
    const int dim = tid & 127, t0 = (tid >> 7) << 4;
    float wA[6], wC[6];
#pragma unroll
    for (int k=0;k<6;++k){ wA[k] = w0Araw[k*128+dim]; wC[k] = w0Braw[k*128+dim]; }
    const float bA_ = ba0[dim], bC_ = bb0[dim];
#pragma unroll
    for (int tt=0;tt<16;++tt){
      int t = t0 + tt;
      float aA = bA_, aC = bC_;
#pragma unroll
      for (int k=0;k<6;++k){
        float xv = xnL[t][k];
        aA += xv * wA[k];
        aC += xv * wC[k];
      }
      UA[t][dim] = aA; UC[t][dim] = aC;
    }
  }
  if (tid < 256){
    int r = tid & 15, cc = tid >> 4;
#pragma unroll
    for (int e=0;e<2;++e){
      int c = cc + e*16;
      float h0 = (c < 3) ? init_ori[(Rbase + r)*3 + c] : 0.f;
      f16 hh = (f16)h0, hl = (f16)(h0 - (float)hh);
      int idx = ((((c>>3)<<4) | r)<<3) + (c&7);
      S[0][0][idx] = hh; S[0][1][idx] = hl;
    }
  }
  __syncthreads();

  for (int t=0; t<67; ++t){
    if (t < 64){
      // ---- L0: Z0 = tanh(U_A + W0A_h^T@h) * tanh(U_C + W0B_h^T@h) ----
      {
        f16x8 Bh = *(const f16x8*)(&S[t&1][0][l<<3]);
        f16x8 Bl = *(const f16x8*)(&S[t&1][1][l<<3]);
        f32x4 aH = *(const f32x4*)(&UA[t][d0]);
        f32x4 cH = *(const f32x4*)(&UC[t][d0]);
        f32x4 aL = {0,0,0,0}, cL = {0,0,0,0};
        aH = MFMA16(w0A, Bh, aH); aL = MFMA16(w0A, Bl, aL);
        cH = MFMA16(w0B, Bh, cH); cL = MFMA16(w0B, Bl, cL);
        f16x4 z4;
#pragma unroll
        for (int i=0;i<4;++i)
          z4[i] = (f16)(tanhfast(aH[i]+aL[i]) * tanhfast(cH[i]+cL[i]));
        int kt_o = d0>>5, lane_o = (((d0&31)>>3)<<4) | n16, j0 = d0&7;
        *(f16x4*)(&Z[0][((kt_o*64 + lane_o)<<3) + j0]) = z4;
      }
      BAR();
      qphase<0>(Z[0], Z[1], wqA[0], wqB[0], bA_r[0], bB_r[0], l, d0, n16);
      BAR();
      qphase<0>(Z[1], Z[0], wqA[1], wqB[1], bA_r[1], bB_r[1], l, d0, n16);
      BAR();
      qphase<1>(Z[0], Z[1], wqA[2], wqB[2], bA_r[2], bB_r[2], l, d0, n16);
      BAR();
    }
    // ---- P4 superphase ----
    if (t < 64 && wid < 2){
      // alpha+beta + h-update; h(t) -> S[(t+1)&1]
      f16x8 q[4];
#pragma unroll
      for (int kt=0;kt<4;++kt) q[kt] = *(const f16x8*)(&Z[1][(kt*64+l)<<3]);
      f32x4 ua = uaB;
      f32x4 ub = ubB;
#pragma unroll
      for (int kt=0;kt<4;++kt){
        ua = MFMA16(wal[kt], q[kt], ua);
        ub = MFMA16(wbe[kt], q[kt], ub);
      }
      float sn = xnL[t][6];
      f16x4 hh4, hl4;
#pragma unroll
      for (int i=0;i<4;++i){
        float alv = expfast(fminf(ua[i], 80.f));
        float bev = tanhfast(ub[i]);
        float hn = __builtin_amdgcn_exp2f(-1.44269504f*alv*sn)*(hreg[i] - bev) + bev;
        hreg[i] = hn;
        f16 hh = (f16)hn; hh4[i] = hh; hl4[i] = (f16)(hn - (float)hh);
      }
      int sb = ((((d0p>>3)<<4) | n16)<<3) + (d0p&7);
      *(f16x4*)(&S[(t+1)&1][0][sb]) = hh4;
      *(f16x4*)(&S[(t+1)&1][1][sb]) = hl4;
    }
    if ((wid == 4 || wid == 5) && t >= 1 && t <= 64){
      // o1(t-1) = tanh(h(t-1) @ W0 + b0); h(t-1) lives in S[t&1][0]
      f16x8 Bh = *(const f16x8*)(&S[t&1][0][l<<3]);
      f16* o1w = &o1buf[(t+1)&1][0];
#pragma unroll
      for (int j=0;j<4;++j){
        int nt = (wid-4)*4 + j;
        f16x8 w = ldWs(WOs, 0, 1, nt, 0, l);
        f32x4 acc = bo0r[j];
        acc = MFMA16(w, Bh, acc);
        f16x4 z4;
#pragma unroll
        for (int i=0;i<4;++i) z4[i] = (f16)tanhfast(acc[i]);
        int d0s = nt*16 + (rhi<<2);
        int kt_o = d0s>>5, lane_o = (((d0s&31)>>3)<<4) | n16, j0 = d0s&7;
        *(f16x4*)(o1w + ((kt_o*64 + lane_o)<<3) + j0) = z4;
      }
    }
    if ((wid == 2 || wid == 3) && t >= 2 && t <= 65){
      // o2(t-2) = tanh(o1(t-2) @ W1 + b1); o1(t-2) lives in o1buf[t&1]
      f16x8 Bq[4];
#pragma unroll
      for (int kt=0;kt<4;++kt) Bq[kt] = *(const f16x8*)(&o1buf[t&1][(kt*64+l)<<3]);
      f16* o2w = &o2buf[t&1][0];
#pragma unroll
      for (int j=0;j<4;++j){
        int nt = (wid-2)*4 + j;
        f32x4 acc = bo1r[j];
#pragma unroll
        for (int kt=0;kt<4;++kt){
          f16x8 w = ldWs(WOs, 4096, 4, nt, kt, l);
          acc = MFMA16(w, Bq[kt], acc);
        }
        f16x4 z4;
#pragma unroll
        for (int i=0;i<4;++i) z4[i] = (f16)tanhfast(acc[i]);
        int d0s = nt*16 + (rhi<<2);
        int kt_o = d0s>>5, lane_o = (((d0s&31)>>3)<<4) | n16, j0 = d0s&7;
        *(f16x4*)(o2w + ((kt_o*64 + lane_o)<<3) + j0) = z4;
      }
    }
    if (wid == 6 && t >= 3){
      // o3(t-3) = o2(t-3) @ W2 + b2 -> out; o2(t-3) lives in o2buf[(t+1)&1]
      f16x8 Bq[4];
#pragma unroll
      for (int kt=0;kt<4;++kt) Bq[kt] = *(const f16x8*)(&o2buf[(t+1)&1][(kt*64+l)<<3]);
      f32x4 acc = {0,0,0,0};
#pragma unroll
      for (int kt=0;kt<4;++kt){
        f16x8 w = ldWs(WOs, 20480, 4, 0, kt, l);
        acc = MFMA16(w, Bq[kt], acc);
      }
      if (l < 16){
        int t3 = t - 3;
        float* op = out + ((Rbase + l)*64 + t3)*3;
        op[0] = acc[0] + b2r0;
        op[1] = acc[1] + b2r1;
        op[2] = acc[2] + b2r2;
      }
    }
    BAR();
  }
}

extern "C" void kernel_launch(void* const* d_in, const int* in_sizes, int n_in,
                              void* d_out, int out_size, void* d_ws, size_t ws_size,
                              hipStream_t stream){
  const float* x        = (const float*)d_in[0];
  const float* init_ori = (const float*)d_in[1];
  f16* wp = (f16*)d_ws;

  PackSrcs ps;
  ps.p[0] = (const float*)d_in[2];   // qbA_W0
  ps.p[1] = (const float*)d_in[6];   // qbB_W0
  ps.p[2] = (const float*)d_in[4];   // qbA_Ws
  ps.p[3] = (const float*)d_in[8];   // qbB_Ws
  ps.p[4] = (const float*)d_in[10];  // alpha_W
  ps.p[5] = (const float*)d_in[12];  // beta_W
  ps.p[6] = (const float*)d_in[14];  // out_W0
  ps.p[7] = (const float*)d_in[16];  // out_W1
  ps.p[8] = (const float*)d_in[18];  // out_W2
  pack_all<<<(PACK_TOTAL+255)/256, 256, 0, stream>>>(ps, wp);

  lmsc_rec<<<128,512,0,stream>>>(x, init_ori, wp,
      (const float*)d_in[2],  (const float*)d_in[6],   // raw W0 for U-precompute
      (const float*)d_in[3],  (const float*)d_in[5],   // qbA_b0, qbA_bs
      (const float*)d_in[7],  (const float*)d_in[9],   // qbB_b0, qbB_bs
      (const float*)d_in[11], (const float*)d_in[13],  // alpha_b, beta_b
      (const float*)d_in[15], (const float*)d_in[17], (const float*)d_in[19],
      (float*)d_out);
}

// Round 12
// 131.940 us; speedup vs baseline: 4.1222x; 1.2614x over previous
//
#include <hip/hip_runtime.h>

typedef _Float16 f16;
typedef _Float16 f16x4 __attribute__((ext_vector_type(4)));
typedef _Float16 f16x8 __attribute__((ext_vector_type(8)));
typedef float f32x4 __attribute__((ext_vector_type(4)));
typedef unsigned int u32;

#define MFMA16(a,b,c) __builtin_amdgcn_mfma_f32_16x16x32_f16(a,b,c,0,0,0)

// raw barrier: orders LDS (lgkmcnt) but does NOT drain vmcnt (neutral vs
// __syncthreads in R3; kept so hG stores never gate a barrier).
#define BAR() asm volatile("s_waitcnt lgkmcnt(0)\n\ts_barrier" ::: "memory")

// packed weight f16-element offsets in d_ws
#define OFF_A0 0
#define OFF_B0 8192
#define OFF_AW 16384
#define OFF_BW 65536
#define OFF_AL 114688
#define OFF_BE 118784
#define OFF_O0 122880
#define OFF_O1 126976
#define OFF_O2 143360
#define PACK_TOTAL 145408
#define OFF_HH 262144                 // h plane (single f16): 8192 mt * 512

struct PackSrcs { const float* p[9]; };

// One fused pack kernel: W[K][N] fp32 -> MFMA fragment order f16.
// frag element (nt,kt,lane,j) = W[kt*32 + (lane>>4)*8 + j][nt*16 + (lane&15)]
// W0 segments: h-rows only, packed into K-tile 0 (packed row k <- source row
// 6+k, k<32); xn rows are handled by the f32 U-precompute in lmsc_rec.
__global__ __launch_bounds__(256) void pack_all(PackSrcs ps, f16* __restrict__ dst){
  int idx = blockIdx.x*256 + threadIdx.x;
  if (idx >= PACK_TOTAL) return;
  const float* src; int base, Kreal, Nreal, KT;
  if (idx < 16384){
    if (idx < 8192){ src=ps.p[0]; base=0; } else { src=ps.p[1]; base=8192; }
    Kreal=38; Nreal=128; KT=2;
  } else if (idx < 65536){
    int s=(idx-16384)>>14; src=ps.p[2]+s*16384; base=16384+s*16384; Kreal=128; Nreal=128; KT=4;
  } else if (idx < 114688){
    int s=(idx-65536)>>14; src=ps.p[3]+s*16384; base=65536+s*16384; Kreal=128; Nreal=128; KT=4;
  } else if (idx < 122880){
    if (idx<118784){ src=ps.p[4]; base=114688; } else { src=ps.p[5]; base=118784; }
    Kreal=128; Nreal=32; KT=4;
  } else if (idx < 126976){
    src=ps.p[6]; base=122880; Kreal=32; Nreal=128; KT=1;
  } else if (idx < 143360){
    src=ps.p[7]; base=126976; Kreal=128; Nreal=128; KT=4;
  } else {
    src=ps.p[8]; base=143360; Kreal=128; Nreal=3; KT=4;
  }
  int local = idx - base;
  int j = local & 7, lane = (local>>3)&63, rem = local>>9;
  int kt = rem % KT, nt = rem / KT;
  int k = kt*32 + ((lane>>4)<<3) + j;
  int n = nt*16 + (lane&15);
  if (base < 16384) k = (k < 32) ? (k + 6) : 99;   // h-rows into tile 0; tile 1 zero
  dst[idx] = (f16)((k<Kreal && n<Nreal) ? src[k*Nreal+n] : 0.f);
}

__device__ __forceinline__ float tanhfast(float x){
  float e = __builtin_amdgcn_exp2f(x * 2.885390082f);   // 2*log2(e)
  return 1.f - 2.f*__builtin_amdgcn_rcpf(e + 1.f);
}
__device__ __forceinline__ float expfast(float x){
  return __builtin_amdgcn_exp2f(x * 1.44269504f);
}

__device__ __forceinline__ f16x8 ldW(const f16* wp, int off, int KT, int nt, int kt, int l){
  return *(const f16x8*)(wp + off + (((nt*KT + kt)*64 + l)<<3));
}

// single-plane quadratic phase (transposed orientation, m=1 per wave)
// bias accumulator-init comes from hoisted REGISTERS (loop-invariant), not LDS.
template<int LAST>
__device__ __forceinline__ void qphase(const f16* __restrict__ Zi, f16* __restrict__ Zo,
                                       const f16x8 (&WA)[4], const f16x8 (&WB)[4],
                                       f32x4 bA4, f32x4 bB4,
                                       int l, int d0, int n16){
  f16x8 Bq[4];
#pragma unroll
  for (int kt=0; kt<4; ++kt) Bq[kt] = *(const f16x8*)(Zi + ((kt*64 + l)<<3));
  f32x4 a = bA4;
  f32x4 c = bB4;
#pragma unroll
  for (int kt=0; kt<4; ++kt){
    a = MFMA16(WA[kt], Bq[kt], a);
    c = MFMA16(WB[kt], Bq[kt], c);
  }
  f16x4 z4;
#pragma unroll
  for (int i=0;i<4;++i){
    float z = LAST ? tanhfast(a[i]*c[i]) : tanhfast(a[i])*tanhfast(c[i]);
    z4[i] = (f16)z;
  }
  int kt_o = d0>>5, lane_o = (((d0&31)>>3)<<4) | n16, j0 = d0&7;
  *(f16x4*)(Zo + ((kt_o*64 + lane_o)<<3) + j0) = z4;
}

// Recurrence: 128 blocks x 512 threads (8 waves, m=1 each, 2 waves/SIMD).
// R6 structure (U-precompute L0, K=32 h-plane, register h in P4) with all
// loop-invariant bias loads hoisted from LDS into registers at init.
__global__ __launch_bounds__(512,2)
void lmsc_rec(const float* __restrict__ x, const float* __restrict__ init_ori,
              const f16* __restrict__ wp,
              const float* __restrict__ w0Araw, const float* __restrict__ w0Braw,
              const float* __restrict__ ba0, const float* __restrict__ bas,
              const float* __restrict__ bb0, const float* __restrict__ bbs,
              const float* __restrict__ b_al, const float* __restrict__ b_be,
              f16* __restrict__ hG)
{
  __shared__ __align__(16) f16 S[2][512];      // [hi|lo] h-plane, K=32 rows
  __shared__ __align__(16) f16 Z[2][2048];     // ping-pong, single plane, K=128
  __shared__ float xnL[64][8];                 // xn[t][0..5], sn at [6]
  __shared__ __align__(16) float UA[64][128];  // ba0 + W0A_xn^T @ xn_t (f32)
  __shared__ __align__(16) float UC[64][128];  // bb0 + W0B_xn^T @ xn_t (f32)

  const int tid = (int)threadIdx.x;
  const int l = tid & 63, wid = tid >> 6;      // 8 waves
  const int n16 = l & 15, rhi = l >> 4;
  const int d0 = (wid<<4) + (rhi<<2);          // this wave's 16-dim slice
  const int tile = (int)blockIdx.x, b = tile >> 4, Rbase = tile << 4;

  // ---- register-resident weight fragments (A-frags of W^T) ----
  f16x8 w0A = ldW(wp, OFF_A0, 2, wid, 0, l);
  f16x8 w0B = ldW(wp, OFF_B0, 2, wid, 0, l);
  f16x8 wqA[3][4], wqB[3][4];
#pragma unroll
  for (int ly=0;ly<3;++ly)
#pragma unroll
    for (int kt=0;kt<4;++kt){
      wqA[ly][kt] = ldW(wp, OFF_AW + ly*16384, 4, wid, kt, l);
      wqB[ly][kt] = ldW(wp, OFF_BW + ly*16384, 4, wid, kt, l);
    }
  // ---- hoisted loop-invariant biases (registers, from global) ----
  f32x4 bA_r[3], bB_r[3];
#pragma unroll
  for (int ly=0;ly<3;++ly){
    bA_r[ly] = *(const f32x4*)(bas + ly*128 + d0);
    bB_r[ly] = *(const f32x4*)(bbs + ly*128 + d0);
  }
  const int d0p = (wid<<4) + (rhi<<2);         // == d0; P4 uses waves 0-1 only
  f16x8 wal[4], wbe[4];
  f32x4 uaB = {0,0,0,0}, ubB = {0,0,0,0};
  if (wid < 2){
#pragma unroll
    for (int kt=0;kt<4;++kt){
      wal[kt] = ldW(wp, OFF_AL, 4, wid, kt, l);
      wbe[kt] = ldW(wp, OFF_BE, 4, wid, kt, l);
    }
    uaB = *(const f32x4*)(b_al + d0p);
    ubB = *(const f32x4*)(b_be + d0p);
  }

  // ---- init ----
  if (tid < 64){
    const float* xp = x + (b*64 + tid)*6;
    float s2 = 0.f;
#pragma unroll
    for (int i=0;i<6;++i) s2 += xp[i]*xp[i];
    float sn = sqrtf(s2);
    float inv = 1.f/(sn + 1e-15f);
#pragma unroll
    for (int i=0;i<6;++i) xnL[tid][i] = xp[i]*inv;
    xnL[tid][6] = sn;
  }
  // h state registers (waves 0-1 only): hreg[i] = h[d0p+i][n16]
  float hreg[4] = {0.f,0.f,0.f,0.f};
  if (wid < 2){
#pragma unroll
    for (int i=0;i<4;++i){
      int c = d0p + i;
      hreg[i] = (c < 3) ? init_ori[(Rbase + n16)*3 + c] : 0.f;
    }
  }
  __syncthreads();
  // U precompute: 4 threads per dim, 16 t each; W0 xn-rows read once per thread.
  {
    const int dim = tid & 127, t0 = (tid >> 7) << 4;
    float wA[6], wC[6];
#pragma unroll
    for (int k=0;k<6;++k){ wA[k] = w0Araw[k*128+dim]; wC[k] = w0Braw[k*128+dim]; }
    const float bA_ = ba0[dim], bC_ = bb0[dim];
#pragma unroll
    for (int tt=0;tt<16;++tt){
      int t = t0 + tt;
      float aA = bA_, aC = bC_;
#pragma unroll
      for (int k=0;k<6;++k){
        float xv = xnL[t][k];
        aA += xv * wA[k];
        aC += xv * wC[k];
      }
      UA[t][dim] = aA; UC[t][dim] = aC;
    }
  }
  if (tid < 256){
    int r = tid & 15, cc = tid >> 4;
#pragma unroll
    for (int e=0;e<2;++e){
      int c = cc + e*16;
      float h0 = (c < 3) ? init_ori[(Rbase + r)*3 + c] : 0.f;
      f16 hh = (f16)h0, hl = (f16)(h0 - (float)hh);
      int idx = ((((c>>3)<<4) | r)<<3) + (c&7);
      S[0][idx] = hh; S[1][idx] = hl;
    }
  }
  __syncthreads();

  for (int t=0; t<64; ++t){
    // ---- L0: Z0 = tanh(U_A + W0A_h^T@h) * tanh(U_C + W0B_h^T@h) ----
    {
      f16x8 Bh = *(const f16x8*)(&S[0][l<<3]);
      f16x8 Bl = *(const f16x8*)(&S[1][l<<3]);
      f32x4 aH = *(const f32x4*)(&UA[t][d0]);
      f32x4 cH = *(const f32x4*)(&UC[t][d0]);
      f32x4 aL = {0,0,0,0}, cL = {0,0,0,0};
      aH = MFMA16(w0A, Bh, aH); aL = MFMA16(w0A, Bl, aL);
      cH = MFMA16(w0B, Bh, cH); cL = MFMA16(w0B, Bl, cL);
      f16x4 z4;
#pragma unroll
      for (int i=0;i<4;++i)
        z4[i] = (f16)(tanhfast(aH[i]+aL[i]) * tanhfast(cH[i]+cL[i]));
      int kt_o = d0>>5, lane_o = (((d0&31)>>3)<<4) | n16, j0 = d0&7;
      *(f16x4*)(&Z[0][((kt_o*64 + lane_o)<<3) + j0]) = z4;
    }
    BAR();
    qphase<0>(Z[0], Z[1], wqA[0], wqB[0], bA_r[0], bB_r[0], l, d0, n16);
    BAR();
    qphase<0>(Z[1], Z[0], wqA[1], wqB[1], bA_r[1], bB_r[1], l, d0, n16);
    BAR();
    qphase<1>(Z[0], Z[1], wqA[2], wqB[2], bA_r[2], bB_r[2], l, d0, n16);
    BAR();
    // ---- P4: alpha+beta+h-update on waves 0-1 (dims d0p<32), h in registers ----
    if (wid < 2){
      f16x8 q[4];
#pragma unroll
      for (int kt=0;kt<4;++kt) q[kt] = *(const f16x8*)(&Z[1][(kt*64+l)<<3]);
      f32x4 ua = uaB;
      f32x4 ub = ubB;
#pragma unroll
      for (int kt=0;kt<4;++kt){
        ua = MFMA16(wal[kt], q[kt], ua);
        ub = MFMA16(wbe[kt], q[kt], ub);
      }
      float sn = xnL[t][6];
      int mt = tile*64 + t;
      f16x4 hh4, hl4;
#pragma unroll
      for (int i=0;i<4;++i){
        float alv = expfast(fminf(ua[i], 80.f));
        float bev = tanhfast(ub[i]);
        float hn = __builtin_amdgcn_exp2f(-1.44269504f*alv*sn)*(hreg[i] - bev) + bev;
        hreg[i] = hn;
        f16 hh = (f16)hn; hh4[i] = hh; hl4[i] = (f16)(hn - (float)hh);
      }
      if (t < 63){
        int sb = ((((d0p>>3)<<4) | n16)<<3) + (d0p&7);
        *(f16x4*)(&S[0][sb]) = hh4;
        *(f16x4*)(&S[1][sb]) = hl4;
      }
      int lane_o = ((d0p>>3)<<4) | n16;
      *(f16x4*)(hG + mt*512 + lane_o*8 + (d0p&7)) = hh4;
    }
    BAR();
  }
}

// Deferred output head: batched GEMM over all 8192 (tile,t) M-tiles, 256 CUs.
__global__ __launch_bounds__(512,4)
void lmsc_out(const f16* __restrict__ wp, const f16* __restrict__ hG,
              const float* __restrict__ bo0, const float* __restrict__ bo1,
              const float* __restrict__ bo2, float* __restrict__ out)
{
  __shared__ __align__(16) f16 o1b[16384];   // [s][kt][lane][8]
  __shared__ __align__(16) f16 o2b[16384];
  const int tid=(int)threadIdx.x, l=tid&63, wid=tid>>6;
  const int n16=l&15, rhi=l>>4;
  const int mtb = (int)blockIdx.x * 8;
  f16x8 W0a = ldW(wp, OFF_O0, 1, wid, 0, l);
  f16x8 W1a[4], W2a[4];
#pragma unroll
  for (int kt=0;kt<4;++kt){ W1a[kt]=ldW(wp,OFF_O1,4,wid,kt,l); W2a[kt]=ldW(wp,OFF_O2,4,0,kt,l); }
  const int d0 = wid*16 + rhi*4;
  const f32x4 b0v = *(const f32x4*)(bo0 + d0);
  const f32x4 b1v = *(const f32x4*)(bo1 + d0);
  const int kt_o = d0>>5, lane_o = (((d0&31)>>3)<<4) + n16, j0 = d0&7;
  // o1 = tanh(h @ W0 + b0), single-plane h
#pragma unroll
  for (int s=0;s<8;++s){
    int mt = mtb + s;
    f16x8 Bh = *(const f16x8*)(hG + ((mt*64+l)<<3));
    f32x4 acc = b0v;
    acc = MFMA16(W0a, Bh, acc);
    f16x4 z4;
#pragma unroll
    for (int i=0;i<4;++i) z4[i] = (f16)tanhfast(acc[i]);
    *(f16x4*)(&o1b[(((s*4+kt_o)*64 + lane_o)<<3) + j0]) = z4;
  }
  __syncthreads();
  // o2 = tanh(o1 @ W1 + b1)
#pragma unroll
  for (int s=0;s<8;++s){
    f32x4 acc = b1v;
#pragma unroll
    for (int kt=0;kt<4;++kt){
      f16x8 B = *(const f16x8*)(&o1b[((s*4+kt)*64 + l)<<3]);
      acc = MFMA16(W1a[kt], B, acc);
    }
    f16x4 z4;
#pragma unroll
    for (int i=0;i<4;++i) z4[i] = (f16)tanhfast(acc[i]);
    *(f16x4*)(&o2b[(((s*4+kt_o)*64 + lane_o)<<3) + j0]) = z4;
  }
  __syncthreads();
  // o3 = o2 @ W2 + b2 -> out; wave w handles subtile w
  {
    f32x4 acc = {0,0,0,0};
#pragma unroll
    for (int kt=0;kt<4;++kt){
      f16x8 B = *(const f16x8*)(&o2b[((wid*4+kt)*64 + l)<<3]);
      acc = MFMA16(W2a[kt], B, acc);
    }
    if (l < 16){
      int mt = mtb + wid, grow = (mt>>6)*16 + n16, tt = mt & 63;
#pragma unroll
      for (int i=0;i<3;++i)
        out[(grow*64 + tt)*3 + i] = acc[i] + bo2[i];
    }
  }
}

extern "C" void kernel_launch(void* const* d_in, const int* in_sizes, int n_in,
                              void* d_out, int out_size, void* d_ws, size_t ws_size,
                              hipStream_t stream){
  const float* x        = (const float*)d_in[0];
  const float* init_ori = (const float*)d_in[1];
  f16* wp = (f16*)d_ws;

  PackSrcs ps;
  ps.p[0] = (const float*)d_in[2];   // qbA_W0
  ps.p[1] = (const float*)d_in[6];   // qbB_W0
  ps.p[2] = (const float*)d_in[4];   // qbA_Ws
  ps.p[3] = (const float*)d_in[8];   // qbB_Ws
  ps.p[4] = (const float*)d_in[10];  // alpha_W
  ps.p[5] = (const float*)d_in[12];  // beta_W
  ps.p[6] = (const float*)d_in[14];  // out_W0
  ps.p[7] = (const float*)d_in[16];  // out_W1
  ps.p[8] = (const float*)d_in[18];  // out_W2
  pack_all<<<(PACK_TOTAL+255)/256, 256, 0, stream>>>(ps, wp);

  lmsc_rec<<<128,512,0,stream>>>(x, init_ori, wp,
      (const float*)d_in[2],  (const float*)d_in[6],   // raw W0 for U-precompute
      (const float*)d_in[3],  (const float*)d_in[5],   // qbA_b0, qbA_bs
      (const float*)d_in[7],  (const float*)d_in[9],   // qbB_b0, qbB_bs
      (const float*)d_in[11], (const float*)d_in[13],  // alpha_b, beta_b
      wp + OFF_HH);
  lmsc_out<<<1024,512,0,stream>>>(wp, wp + OFF_HH,
      (const float*)d_in[15], (const float*)d_in[17], (const float*)d_in[19],
      (float*)d_out);
}